// Round 5
// baseline (66.226 us; speedup 1.0000x reference)
//
#include <hip/hip_runtime.h>

// ShiftMap fused, v5:
//  - kernel 1: x-interpolate 16x16 control grid to Xsc[b][16][1024] (float2,
//    pre-scaled) in d_ws.
//  - kernel 2: 3-phase per-thread pipeline: (A) all xsc loads, (B) all
//    coords/weights, (C) gathers as unaligned float4 row-loads + FMA.
//  - XCD-aware swizzle keeps each batch's 4MB image in one XCD's L2.

static constexpr float A = -0.75f;  // PyTorch bicubic coefficient
static constexpr int NXCD = 8;

typedef float f4u __attribute__((ext_vector_type(4), aligned(4)));

__device__ __forceinline__ void cubic_weights(float t, float* w) {
    float t2 = t * t;
    float s  = 1.0f - t;
    w[1] = (A + 2.0f) * t * t2 - (A + 3.0f) * t2 + 1.0f;       // dist = t
    w[2] = (A + 2.0f) * s * s * s - (A + 3.0f) * s * s + 1.0f; // dist = 1-t
    float u = 1.0f + t;
    w[0] = A * (u * (u * (u - 5.0f) + 8.0f) - 4.0f);           // dist = 1+t
    float v = 2.0f - t;
    w[3] = A * (v * (v * (v - 5.0f) + 8.0f) - 4.0f);           // dist = 2-t
}

// ---- kernel 1: Xsc[b][cy][x] = (smy(x)*half_h, smx(x)*half_w) ----
__global__ __launch_bounds__(256) void xinterp_kernel(
    const float* __restrict__ smap,  // (B,CH,CW,2)
    float2* __restrict__ xsc,        // (B,CH,W)
    int W, int CH, int CW, float scale_x, float half_h, float half_w)
{
    const int x  = blockIdx.x * 256 + threadIdx.x;
    const int cy = blockIdx.y;
    const int b  = blockIdx.z;
    if (x >= W) return;

    const float sx  = x * scale_x;
    const float fx0 = floorf(sx);
    const int   cx0 = (int)fx0;
    float wx[4];
    cubic_weights(sx - fx0, wx);

    const float* row = smap + (((size_t)b * CH + cy) * CW) * 2;
    float vy = 0.0f, vx = 0.0f;
    #pragma unroll
    for (int j = 0; j < 4; ++j) {
        const int cx = min(max(cx0 - 1 + j, 0), CW - 1);
        vy += wx[j] * row[cx * 2 + 0];
        vx += wx[j] * row[cx * 2 + 1];
    }
    xsc[((size_t)b * CH + cy) * W + x] = make_float2(vy * half_h, vx * half_w);
}

// ---- kernel 2: warp ----
template <int PX>
__global__ __launch_bounds__(256, 4) void shiftmap_warp_kernel(
    const float* __restrict__ img,    // (B,1,H,W)
    const float2* __restrict__ xsc,   // (B,CH,W)
    float* __restrict__ out,          // (B,1,H,W)
    int H, int W, int CH, int nblocks, float scale_y)
{
    // XCD-aware swizzle: dispatch d lands on XCD d%8 -> contiguous work band.
    const int d    = blockIdx.x;
    const int per  = nblocks / NXCD;
    const int work = (d % NXCD) * per + d / NXCD;
    const int y = work % H;
    const int b = work / H;
    const int tid = threadIdx.x;

    // row-uniform y-interp weights + clamped control-row base pointers
    const float sy  = y * scale_y;
    const float fy0 = floorf(sy);
    const int   cy0 = (int)fy0;
    float wy[4];
    cubic_weights(sy - fy0, wy);
    const float2* xb  = xsc + (size_t)b * CH * W;
    const float2* bp0 = xb + (size_t)min(max(cy0 - 1, 0), CH - 1) * W;
    const float2* bp1 = xb + (size_t)min(max(cy0    , 0), CH - 1) * W;
    const float2* bp2 = xb + (size_t)min(max(cy0 + 1, 0), CH - 1) * W;
    const float2* bp3 = xb + (size_t)min(max(cy0 + 2, 0), CH - 1) * W;

    const float* imgb = img + (size_t)b * H * W;
    float* outb = out + (size_t)b * H * W + (size_t)y * W;

    // ---- Phase A: issue ALL xsc tap loads (coalesced, independent) ----
    float2 c0[PX], c1[PX], c2[PX], c3[PX];
    #pragma unroll
    for (int k = 0; k < PX; ++k) {
        const int x = tid + k * 256;
        c0[k] = bp0[x]; c1[k] = bp1[x]; c2[k] = bp2[x]; c3[k] = bp3[x];
    }

    // ---- Phase B: coords, weights, base addresses for all PX pixels ----
    float gwx[PX][4], gwy[PX][4];
    int ix0[PX], iy0[PX];
    bool inter[PX];
    #pragma unroll
    for (int k = 0; k < PX; ++k) {
        const int x = tid + k * 256;
        const float smy = wy[0] * c0[k].x + wy[1] * c1[k].x
                        + wy[2] * c2[k].x + wy[3] * c3[k].x;
        const float smx = wy[0] * c0[k].y + wy[1] * c1[k].y
                        + wy[2] * c2[k].y + wy[3] * c3[k].y;
        const float ix = (float)x + smx;
        const float iy = (float)y + smy;
        const float ixf = floorf(ix), iyf = floorf(iy);
        ix0[k] = (int)ixf; iy0[k] = (int)iyf;
        cubic_weights(ix - ixf, gwx[k]);
        cubic_weights(iy - iyf, gwy[k]);
        inter[k] = (ix0[k] >= 1) & (ix0[k] <= W - 3) & (iy0[k] >= 1) & (iy0[k] <= H - 3);
    }

    // ---- Phase C: gathers (float4 row-loads) + FMA + store ----
    #pragma unroll
    for (int k = 0; k < PX; ++k) {
        const int x = tid + k * 256;
        float acc = 0.0f;
        if (inter[k]) {
            const float* p = imgb + (size_t)(iy0[k] - 1) * W + (ix0[k] - 1);
            const f4u r0 = *reinterpret_cast<const f4u*>(p);
            const f4u r1 = *reinterpret_cast<const f4u*>(p + W);
            const f4u r2 = *reinterpret_cast<const f4u*>(p + 2 * W);
            const f4u r3 = *reinterpret_cast<const f4u*>(p + 3 * W);
            const float* wxk = gwx[k];
            acc  = gwy[k][0] * (wxk[0] * r0.x + wxk[1] * r0.y + wxk[2] * r0.z + wxk[3] * r0.w);
            acc += gwy[k][1] * (wxk[0] * r1.x + wxk[1] * r1.y + wxk[2] * r1.z + wxk[3] * r1.w);
            acc += gwy[k][2] * (wxk[0] * r2.x + wxk[1] * r2.y + wxk[2] * r2.z + wxk[3] * r2.w);
            acc += gwy[k][3] * (wxk[0] * r3.x + wxk[1] * r3.y + wxk[2] * r3.z + wxk[3] * r3.w);
        } else {
            // border: zeros padding with per-tap masks
            #pragma unroll
            for (int i = 0; i < 4; ++i) {
                const int yy = iy0[k] - 1 + i;
                const bool vy = (yy >= 0) && (yy < H);
                const int yc = min(max(yy, 0), H - 1);
                const float* row = imgb + (size_t)yc * W;
                float r = 0.0f;
                #pragma unroll
                for (int j = 0; j < 4; ++j) {
                    const int xx = ix0[k] - 1 + j;
                    const bool v = vy && (xx >= 0) && (xx < W);
                    const int xc = min(max(xx, 0), W - 1);
                    r += gwx[k][j] * (v ? row[xc] : 0.0f);
                }
                acc += gwy[k][i] * r;
            }
        }
        outb[x] = acc;
    }
}

// ---- fallback (v3 single-kernel) if ws_size is too small ----
template <int PX_PER_THREAD>
__global__ __launch_bounds__(256) void shiftmap_warp_fallback(
    const float* __restrict__ img, const float* __restrict__ smap,
    float* __restrict__ out, int H, int W, int CH, int CW, int nblocks)
{
    const int d   = blockIdx.x;
    const int per = nblocks / NXCD;
    const int work = (d % NXCD) * per + d / NXCD;
    const int y = work % H;
    const int b = work / H;
    const int tid = threadIdx.x;

    __shared__ float s_row[64];
    const float scale_y = (float)((double)(CH - 1) / (double)(H - 1));
    const float scale_x = (float)((double)(CW - 1) / (double)(W - 1));

    if (tid < CW * 2) {
        const int c = tid >> 1, ch = tid & 1;
        const float sy = y * scale_y;
        const float fy0 = floorf(sy);
        const int cy0 = (int)fy0;
        float wy[4];
        cubic_weights(sy - fy0, wy);
        float v = 0.0f;
        #pragma unroll
        for (int i = 0; i < 4; ++i) {
            const int cy = min(max(cy0 - 1 + i, 0), CH - 1);
            v += wy[i] * smap[(((size_t)b * CH + cy) * CW + c) * 2 + ch];
        }
        s_row[tid] = v;
    }
    __syncthreads();

    const float half_w = 0.5f * (float)(W - 1);
    const float half_h = 0.5f * (float)(H - 1);
    const float* imgb = img + (size_t)b * H * W;
    float* outb = out + (size_t)b * H * W + (size_t)y * W;

    #pragma unroll
    for (int k = 0; k < PX_PER_THREAD; ++k) {
        const int x = tid + k * 256;
        const float sx = x * scale_x;
        const float fx0 = floorf(sx);
        const int cx0 = (int)fx0;
        float wx[4];
        cubic_weights(sx - fx0, wx);
        float smy = 0.0f, smx = 0.0f;
        #pragma unroll
        for (int j = 0; j < 4; ++j) {
            const int cx = min(max(cx0 - 1 + j, 0), CW - 1);
            smy += wx[j] * s_row[cx * 2 + 0];
            smx += wx[j] * s_row[cx * 2 + 1];
        }
        const float ix = (float)x + smx * half_w;
        const float iy = (float)y + smy * half_h;
        const float ixf = floorf(ix), iyf = floorf(iy);
        const int ix0 = (int)ixf, iy0 = (int)iyf;
        float gwx[4], gwy[4];
        cubic_weights(ix - ixf, gwx);
        cubic_weights(iy - iyf, gwy);
        float acc = 0.0f;
        #pragma unroll
        for (int i = 0; i < 4; ++i) {
            const int yy = iy0 - 1 + i;
            const bool vy = (yy >= 0) && (yy < H);
            const int yc = min(max(yy, 0), H - 1);
            const float* row = imgb + (size_t)yc * W;
            float r = 0.0f;
            #pragma unroll
            for (int j = 0; j < 4; ++j) {
                const int xx = ix0 - 1 + j;
                const bool v = vy && (xx >= 0) && (xx < W);
                const int xc = min(max(xx, 0), W - 1);
                r += gwx[j] * (v ? row[xc] : 0.0f);
            }
            acc += gwy[i] * r;
        }
        outb[x] = acc;
    }
}

extern "C" void kernel_launch(void* const* d_in, const int* in_sizes, int n_in,
                              void* d_out, int out_size, void* d_ws, size_t ws_size,
                              hipStream_t stream) {
    const float* img  = (const float*)d_in[0];  // (B,1,1024,1024) fp32
    const float* smap = (const float*)d_in[1];  // (B,16,16,2) fp32
    float* out = (float*)d_out;

    const int H = 1024, W = 1024;
    const int CH = 16, CW = 16;
    const int B = in_sizes[0] / (H * W);
    const int nblocks = H * B;

    const float scale_y = (float)((double)(CH - 1) / (double)(H - 1));
    const float scale_x = (float)((double)(CW - 1) / (double)(W - 1));
    const float half_h = 0.5f * (float)(H - 1);
    const float half_w = 0.5f * (float)(W - 1);

    const size_t ws_needed = (size_t)B * CH * W * sizeof(float2);
    if (ws_size >= ws_needed) {
        float2* xsc = (float2*)d_ws;
        dim3 g1(W / 256, CH, B);
        xinterp_kernel<<<g1, 256, 0, stream>>>(smap, xsc, W, CH, CW,
                                               scale_x, half_h, half_w);
        dim3 g2(nblocks);
        shiftmap_warp_kernel<4><<<g2, 256, 0, stream>>>(img, xsc, out,
                                                        H, W, CH, nblocks, scale_y);
    } else {
        dim3 g2(nblocks);
        shiftmap_warp_fallback<4><<<g2, 256, 0, stream>>>(img, smap, out,
                                                          H, W, CH, CW, nblocks);
    }
}

// Round 6
// 65.338 us; speedup vs baseline: 1.0136x; 1.0136x over previous
//
#include <hip/hip_runtime.h>

// ShiftMap fused, v6:
//  - kernel 1: x-interpolate 16x16 control grid to Xsc[b][16][1024] (float2,
//    pre-scaled) in d_ws.
//  - kernel 2: BRANCHLESS gather — clamped addresses always valid, zeros
//    padding folded into weights (y-mask + x-window remap). All PX*4 float4
//    gathers issue unconditionally -> 16-deep MLP per thread.
//  - XCD-aware swizzle keeps each batch's 4MB image in one XCD's L2.

static constexpr float A = -0.75f;  // PyTorch bicubic coefficient
static constexpr int NXCD = 8;

typedef float f4u __attribute__((ext_vector_type(4), aligned(4)));

__device__ __forceinline__ void cubic_weights(float t, float* w) {
    float t2 = t * t;
    float s  = 1.0f - t;
    w[1] = (A + 2.0f) * t * t2 - (A + 3.0f) * t2 + 1.0f;       // dist = t
    w[2] = (A + 2.0f) * s * s * s - (A + 3.0f) * s * s + 1.0f; // dist = 1-t
    float u = 1.0f + t;
    w[0] = A * (u * (u * (u - 5.0f) + 8.0f) - 4.0f);           // dist = 1+t
    float v = 2.0f - t;
    w[3] = A * (v * (v * (v - 5.0f) + 8.0f) - 4.0f);           // dist = 2-t
}

// ---- kernel 1: Xsc[b][cy][x] = (smy(x)*half_h, smx(x)*half_w) ----
__global__ __launch_bounds__(256) void xinterp_kernel(
    const float* __restrict__ smap,  // (B,CH,CW,2)
    float2* __restrict__ xsc,        // (B,CH,W)
    int W, int CH, int CW, float scale_x, float half_h, float half_w)
{
    const int x  = blockIdx.x * 256 + threadIdx.x;
    const int cy = blockIdx.y;
    const int b  = blockIdx.z;
    if (x >= W) return;

    const float sx  = x * scale_x;
    const float fx0 = floorf(sx);
    const int   cx0 = (int)fx0;
    float wx[4];
    cubic_weights(sx - fx0, wx);

    const float* row = smap + (((size_t)b * CH + cy) * CW) * 2;
    float vy = 0.0f, vx = 0.0f;
    #pragma unroll
    for (int j = 0; j < 4; ++j) {
        const int cx = min(max(cx0 - 1 + j, 0), CW - 1);
        vy += wx[j] * row[cx * 2 + 0];
        vx += wx[j] * row[cx * 2 + 1];
    }
    xsc[((size_t)b * CH + cy) * W + x] = make_float2(vy * half_h, vx * half_w);
}

// ---- kernel 2: warp, branchless gather ----
template <int PX>
__global__ __launch_bounds__(256, 3) void shiftmap_warp_kernel(
    const float* __restrict__ img,    // (B,1,H,W)
    const float2* __restrict__ xsc,   // (B,CH,W)
    float* __restrict__ out,          // (B,1,H,W)
    int H, int W, int CH, int nblocks, float scale_y)
{
    // XCD-aware swizzle: dispatch d lands on XCD d%8 -> contiguous work band.
    const int d    = blockIdx.x;
    const int per  = nblocks / NXCD;
    const int work = (d % NXCD) * per + d / NXCD;
    const int y = work % H;
    const int b = work / H;
    const int tid = threadIdx.x;

    // row-uniform y-interp weights + clamped control-row base pointers
    const float sy  = y * scale_y;
    const float fy0 = floorf(sy);
    const int   cy0 = (int)fy0;
    float wy[4];
    cubic_weights(sy - fy0, wy);
    const float2* xb_  = xsc + (size_t)b * CH * W;
    const float2* bp0 = xb_ + (size_t)min(max(cy0 - 1, 0), CH - 1) * W;
    const float2* bp1 = xb_ + (size_t)min(max(cy0    , 0), CH - 1) * W;
    const float2* bp2 = xb_ + (size_t)min(max(cy0 + 1, 0), CH - 1) * W;
    const float2* bp3 = xb_ + (size_t)min(max(cy0 + 2, 0), CH - 1) * W;

    const float* imgb = img + (size_t)b * H * W;
    float* outb = out + (size_t)b * H * W + (size_t)y * W;

    // ---- Phase A: issue ALL xsc tap loads (coalesced, independent) ----
    float2 c0[PX], c1[PX], c2[PX], c3[PX];
    #pragma unroll
    for (int k = 0; k < PX; ++k) {
        const int x = tid + k * 256;
        c0[k] = bp0[x]; c1[k] = bp1[x]; c2[k] = bp2[x]; c3[k] = bp3[x];
    }

    // ---- Phase B: coords, masked weights, clamped offsets (branch-free
    //      w.r.t. the gather loads) ----
    float wxm[PX][4];   // x weights, border-remapped
    float wym[PX][4];   // y weights, OOB-masked
    int   off[PX][4];   // element offsets of the 4 row-loads (always valid)
    #pragma unroll
    for (int k = 0; k < PX; ++k) {
        const int x = tid + k * 256;
        const float smy = wy[0] * c0[k].x + wy[1] * c1[k].x
                        + wy[2] * c2[k].x + wy[3] * c3[k].x;
        const float smx = wy[0] * c0[k].y + wy[1] * c1[k].y
                        + wy[2] * c2[k].y + wy[3] * c3[k].y;
        const float ix = (float)x + smx;
        const float iy = (float)y + smy;
        const float ixf = floorf(ix), iyf = floorf(iy);
        const int ix0 = (int)ixf, iy0 = (int)iyf;
        float gwx[4], gwy[4];
        cubic_weights(ix - ixf, gwx);
        cubic_weights(iy - iyf, gwy);

        // clamped x-base; delta != 0 only near left/right borders
        const int xb = min(max(ix0 - 1, 0), W - 4);
        const int delta = xb - (ix0 - 1);

        float w0 = gwx[0], w1 = gwx[1], w2 = gwx[2], w3 = gwx[3];
        if (delta != 0) {  // rare: remap weights to the shifted window
            float n0 = 0.f, n1 = 0.f, n2 = 0.f, n3 = 0.f;
            if      (delta ==  1) { n0 = gwx[1]; n1 = gwx[2]; n2 = gwx[3]; }
            else if (delta ==  2) { n0 = gwx[2]; n1 = gwx[3]; }
            else if (delta ==  3) { n0 = gwx[3]; }
            else if (delta == -1) { n1 = gwx[0]; n2 = gwx[1]; n3 = gwx[2]; }
            else if (delta == -2) { n2 = gwx[0]; n3 = gwx[1]; }
            else if (delta == -3) { n3 = gwx[0]; }
            w0 = n0; w1 = n1; w2 = n2; w3 = n3;
        }
        wxm[k][0] = w0; wxm[k][1] = w1; wxm[k][2] = w2; wxm[k][3] = w3;

        #pragma unroll
        for (int i = 0; i < 4; ++i) {
            const int yy = iy0 - 1 + i;
            const bool vy_ok = (yy >= 0) & (yy < H);
            const int yc = min(max(yy, 0), H - 1);
            wym[k][i] = vy_ok ? gwy[i] : 0.0f;
            off[k][i] = yc * W + xb;
        }
    }

    // ---- Phase C: ALL gathers unconditional (16 dwordx4 in flight) ----
    f4u f[PX][4];
    #pragma unroll
    for (int k = 0; k < PX; ++k) {
        #pragma unroll
        for (int i = 0; i < 4; ++i)
            f[k][i] = *reinterpret_cast<const f4u*>(imgb + off[k][i]);
    }

    // ---- Phase D: FMA + store ----
    #pragma unroll
    for (int k = 0; k < PX; ++k) {
        const int x = tid + k * 256;
        float acc = 0.0f;
        #pragma unroll
        for (int i = 0; i < 4; ++i) {
            acc += wym[k][i] * (wxm[k][0] * f[k][i].x + wxm[k][1] * f[k][i].y
                              + wxm[k][2] * f[k][i].z + wxm[k][3] * f[k][i].w);
        }
        outb[x] = acc;
    }
}

// ---- fallback (v3 single-kernel) if ws_size is too small ----
template <int PX_PER_THREAD>
__global__ __launch_bounds__(256) void shiftmap_warp_fallback(
    const float* __restrict__ img, const float* __restrict__ smap,
    float* __restrict__ out, int H, int W, int CH, int CW, int nblocks)
{
    const int d   = blockIdx.x;
    const int per = nblocks / NXCD;
    const int work = (d % NXCD) * per + d / NXCD;
    const int y = work % H;
    const int b = work / H;
    const int tid = threadIdx.x;

    __shared__ float s_row[64];
    const float scale_y = (float)((double)(CH - 1) / (double)(H - 1));
    const float scale_x = (float)((double)(CW - 1) / (double)(W - 1));

    if (tid < CW * 2) {
        const int c = tid >> 1, ch = tid & 1;
        const float sy = y * scale_y;
        const float fy0 = floorf(sy);
        const int cy0 = (int)fy0;
        float wy[4];
        cubic_weights(sy - fy0, wy);
        float v = 0.0f;
        #pragma unroll
        for (int i = 0; i < 4; ++i) {
            const int cy = min(max(cy0 - 1 + i, 0), CH - 1);
            v += wy[i] * smap[(((size_t)b * CH + cy) * CW + c) * 2 + ch];
        }
        s_row[tid] = v;
    }
    __syncthreads();

    const float half_w = 0.5f * (float)(W - 1);
    const float half_h = 0.5f * (float)(H - 1);
    const float* imgb = img + (size_t)b * H * W;
    float* outb = out + (size_t)b * H * W + (size_t)y * W;

    #pragma unroll
    for (int k = 0; k < PX_PER_THREAD; ++k) {
        const int x = tid + k * 256;
        const float sx = x * scale_x;
        const float fx0 = floorf(sx);
        const int cx0 = (int)fx0;
        float wx[4];
        cubic_weights(sx - fx0, wx);
        float smy = 0.0f, smx = 0.0f;
        #pragma unroll
        for (int j = 0; j < 4; ++j) {
            const int cx = min(max(cx0 - 1 + j, 0), CW - 1);
            smy += wx[j] * s_row[cx * 2 + 0];
            smx += wx[j] * s_row[cx * 2 + 1];
        }
        const float ix = (float)x + smx * half_w;
        const float iy = (float)y + smy * half_h;
        const float ixf = floorf(ix), iyf = floorf(iy);
        const int ix0 = (int)ixf, iy0 = (int)iyf;
        float gwx[4], gwy[4];
        cubic_weights(ix - ixf, gwx);
        cubic_weights(iy - iyf, gwy);
        float acc = 0.0f;
        #pragma unroll
        for (int i = 0; i < 4; ++i) {
            const int yy = iy0 - 1 + i;
            const bool vy = (yy >= 0) && (yy < H);
            const int yc = min(max(yy, 0), H - 1);
            const float* row = imgb + (size_t)yc * W;
            float r = 0.0f;
            #pragma unroll
            for (int j = 0; j < 4; ++j) {
                const int xx = ix0 - 1 + j;
                const bool v = vy && (xx >= 0) && (xx < W);
                const int xc = min(max(xx, 0), W - 1);
                r += gwx[j] * (v ? row[xc] : 0.0f);
            }
            acc += gwy[i] * r;
        }
        outb[x] = acc;
    }
}

extern "C" void kernel_launch(void* const* d_in, const int* in_sizes, int n_in,
                              void* d_out, int out_size, void* d_ws, size_t ws_size,
                              hipStream_t stream) {
    const float* img  = (const float*)d_in[0];  // (B,1,1024,1024) fp32
    const float* smap = (const float*)d_in[1];  // (B,16,16,2) fp32
    float* out = (float*)d_out;

    const int H = 1024, W = 1024;
    const int CH = 16, CW = 16;
    const int B = in_sizes[0] / (H * W);
    const int nblocks = H * B;

    const float scale_y = (float)((double)(CH - 1) / (double)(H - 1));
    const float scale_x = (float)((double)(CW - 1) / (double)(W - 1));
    const float half_h = 0.5f * (float)(H - 1);
    const float half_w = 0.5f * (float)(W - 1);

    const size_t ws_needed = (size_t)B * CH * W * sizeof(float2);
    if (ws_size >= ws_needed) {
        float2* xsc = (float2*)d_ws;
        dim3 g1(W / 256, CH, B);
        xinterp_kernel<<<g1, 256, 0, stream>>>(smap, xsc, W, CH, CW,
                                               scale_x, half_h, half_w);
        dim3 g2(nblocks);
        shiftmap_warp_kernel<4><<<g2, 256, 0, stream>>>(img, xsc, out,
                                                        H, W, CH, nblocks, scale_y);
    } else {
        dim3 g2(nblocks);
        shiftmap_warp_fallback<4><<<g2, 256, 0, stream>>>(img, smap, out,
                                                          H, W, CH, CW, nblocks);
    }
}